// Round 4
// baseline (259.296 us; speedup 1.0000x reference)
//
#include <hip/hip_runtime.h>

// SubjectConditionalLinear: y[b,n,o] = sum_h x[b,n,h] * W[sid[b],o,h] + bias[sid[b],o]
// x: [32,512,1024] f32, subject_id: [32] i32, weight: [8,1024,1024] f32, bias: [8,1024] f32
// out: [32,512,1024] f32
//
// R8: single fused kernel. R6's proven LDS geometry (bf16, 128B rows, 8-chunk
// ^(row&7) XOR swizzle, 0 bank conflicts) is kept byte-identical; staging is
// now reg-staged (T14): global f32 -> VGPR -> v_cvt_pk_bf16_f32 ->
// ds_write_b128 (linear, conflict-free). No cvt kernel, no workspace.
// R7's mistake (f32 LDS + 64B-row B swizzle -> 5.2M conflicts) reverted.
//
// Ledger per kt (2 LDS buffers, 4 snake phases, 1 barrier each):
//  P0-tail: issue A-gloads(kt+1) x8; hoisted bfH(kt) reads.
//  P1-tail: VMW(0) [A landed, 1-phase ~1600cyc lead >900cyc HBM]; cvt;
//           4x ds_write A(kt+1)->AO; SB0; issue B-gloads(kt+1) x8;
//           hoisted afH(kt) reads; lgkmcnt(8) retires writes (DS in-order),
//           leaves 8 reads in flight; BAR.
//  P2-tail: VMW(0) [B landed]; cvt; ds_write B(kt+1)->BO; lgkmcnt(0); BAR.
//  P3-tail: hoisted afL/bfL(kt+1) reads (A published 2 bars ago, B 1 bar).
// Every LDS overwrite lands >=2 barriers after its readers' retiring LGKM0.

constexpr int S_DIM = 8;
constexpr int O_DIM = 1024;
constexpr int H_DIM = 1024;
constexpr int B_DIM = 32;
constexpr int N_DIM = 512;

constexpr int BM = 256;
constexpr int BN = 256;
constexpr int BK = 64;
constexpr int NKT = H_DIM / BK;  // 16 K-tiles

typedef short bf16x8 __attribute__((ext_vector_type(8)));
typedef float f32x4 __attribute__((ext_vector_type(4)));
typedef float f32x2 __attribute__((ext_vector_type(2)));
typedef __bf16 bf16x2 __attribute__((ext_vector_type(2)));
typedef unsigned int u32x4 __attribute__((ext_vector_type(4)));

__device__ __forceinline__ unsigned int cvt_pk_bf16(float a, float b) {
  f32x2 v;
  v[0] = a;
  v[1] = b;
  bf16x2 r = __builtin_convertvector(v, bf16x2);  // v_cvt_pk_bf16_f32
  return __builtin_bit_cast(unsigned int, r);
}

#define BAR() __builtin_amdgcn_s_barrier()
#define SB0() __builtin_amdgcn_sched_barrier(0)
#define VMW(N) asm volatile("s_waitcnt vmcnt(" #N ")" ::: "memory")
#define LGKMW(N) asm volatile("s_waitcnt lgkmcnt(" #N ")" ::: "memory")
#define LGKM0()                                            \
  do {                                                     \
    asm volatile("s_waitcnt lgkmcnt(0)" ::: "memory");     \
    __builtin_amdgcn_sched_barrier(0);                     \
  } while (0)

// ---- fragment reads (R6-identical geometry) -------------------------------
// A-fragment quad into DST: rows wr*128 + (MB..MB+3)*16 + lcol, both kk halves.
#define LDA4T(DST, ABUF, MB)                                             \
  do {                                                                   \
    _Pragma("unroll") for (int m_ = 0; m_ < 4; ++m_) {                   \
      const int ar_ = wr * 128 + ((MB) + m_) * 16 + lcol;                \
      const unsigned short* ap_ = (ABUF) + ar_ * BK;                     \
      DST[m_][0] = *(const bf16x8*)(ap_ + (pc0 << 3));                   \
      DST[m_][1] = *(const bf16x8*)(ap_ + ((pc0 ^ 4) << 3));             \
    }                                                                    \
  } while (0)

// B-fragment pair into DST: rows wc*64 + (NB..NB+1)*16 + lcol, both kk halves.
#define LDB2T(DST, BBUF, NB)                                             \
  do {                                                                   \
    _Pragma("unroll") for (int n_ = 0; n_ < 2; ++n_) {                   \
      const int br_ = wc * 64 + ((NB) + n_) * 16 + lcol;                 \
      const unsigned short* bp_ = (BBUF) + br_ * BK;                     \
      DST[n_][0] = *(const bf16x8*)(bp_ + (pc0 << 3));                   \
      DST[n_][1] = *(const bf16x8*)(bp_ + ((pc0 ^ 4) << 3));             \
    }                                                                    \
  } while (0)

// One C-quadrant x K=64: 4m x 2n x 2kk = 16 MFMA.
#define MM4(AF, BF, MB, NB)                                                 \
  do {                                                                      \
    _Pragma("unroll") for (int m_ = 0; m_ < 4; ++m_)                        \
    _Pragma("unroll") for (int n_ = 0; n_ < 2; ++n_)                        \
    _Pragma("unroll") for (int x_ = 0; x_ < 2; ++x_)                        \
      acc[(MB) + m_][(NB) + n_] = __builtin_amdgcn_mfma_f32_16x16x32_bf16(  \
          AF[m_][x_], BF[n_][x_], acc[(MB) + m_][(NB) + n_], 0, 0, 0);      \
  } while (0)

// ---- reg-staging: global f32 -> VGPR -> cvt -> ds_write bf16 --------------
// Thread covers rows wid*32 + i*8 + rl (i=0..3), logical k-chunk (lane&7)^rl
// (8 f32 = 32B = 2 f32x4), written to phys chunk lane&7 of its row.
#define GLOADA(KT)                                                         \
  do {                                                                     \
    _Pragma("unroll") for (int i_ = 0; i_ < 4; ++i_) {                     \
      const float* p_ = agA + (size_t)i_ * 8 * H_DIM + (size_t)(KT) * 64;  \
      ga[i_][0] = *(const f32x4*)p_;                                       \
      ga[i_][1] = *(const f32x4*)(p_ + 4);                                 \
    }                                                                      \
  } while (0)

#define GLOADB(KT)                                                         \
  do {                                                                     \
    _Pragma("unroll") for (int i_ = 0; i_ < 4; ++i_) {                     \
      const float* p_ = bgB + (size_t)i_ * 8 * H_DIM + (size_t)(KT) * 64;  \
      gb[i_][0] = *(const f32x4*)p_;                                       \
      gb[i_][1] = *(const f32x4*)(p_ + 4);                                 \
    }                                                                      \
  } while (0)

#define DSWR(SRC, DST)                                                     \
  do {                                                                     \
    _Pragma("unroll") for (int i_ = 0; i_ < 4; ++i_) {                     \
      u32x4 t_;                                                            \
      t_[0] = cvt_pk_bf16(SRC[i_][0][0], SRC[i_][0][1]);                   \
      t_[1] = cvt_pk_bf16(SRC[i_][0][2], SRC[i_][0][3]);                   \
      t_[2] = cvt_pk_bf16(SRC[i_][1][0], SRC[i_][1][1]);                   \
      t_[3] = cvt_pk_bf16(SRC[i_][1][2], SRC[i_][1][3]);                   \
      *(u32x4*)((DST) + swoff + i_ * 8 * BK) = t_;                         \
    }                                                                      \
  } while (0)

// One K-tile, 4 snake phases.
#define KTILE(KT, AC, BC, AO, BO)                                        \
  do {                                                                   \
    /* P0: Q(lo-m, lo-n) — af=lo(KT), bfL(KT) read in prev P3 tail */    \
    LGKM0();                                                             \
    __builtin_amdgcn_s_setprio(1);                                       \
    MM4(af, bfL, 0, 0);                                                  \
    __builtin_amdgcn_s_setprio(0);                                       \
    if ((KT) + 1 < NKT) GLOADA((KT) + 1);                                \
    LDB2T(bfH, BC, 2);                /* bf_hi(KT) for P1 */             \
    SB0();                                                               \
    BAR();                                                               \
    /* P1: Q(lo-m, hi-n) */                                              \
    LGKM0();                                                             \
    __builtin_amdgcn_s_setprio(1);                                       \
    MM4(af, bfH, 0, 2);                                                  \
    __builtin_amdgcn_s_setprio(0);                                       \
    if ((KT) + 1 < NKT) {                                                \
      VMW(0);        /* A(KT+1) landed (issued 1 phase ago) */           \
      DSWR(ga, AO);                                                      \
      SB0();         /* pin writes before reads for lgkmcnt(8) */        \
      GLOADB((KT) + 1);                                                  \
    }                                                                    \
    LDA4T(af, AC, 4);                 /* af_hi(KT) for P2/P3 */          \
    LGKMW(8);        /* retire the 4 ds_writes (DS in-order) */          \
    SB0();                                                               \
    BAR();                                                               \
    /* P2: Q(hi-m, hi-n) */                                              \
    LGKM0();                                                             \
    __builtin_amdgcn_s_setprio(1);                                       \
    MM4(af, bfH, 4, 2);                                                  \
    __builtin_amdgcn_s_setprio(0);                                       \
    if ((KT) + 1 < NKT) {                                                \
      VMW(0);        /* B(KT+1) landed */                                \
      DSWR(gb, BO);                                                      \
      LGKMW(0);      /* publish B writes before BAR */                   \
    }                                                                    \
    SB0();                                                               \
    BAR();                                                               \
    /* P3: Q(hi-m, lo-n) */                                              \
    LGKM0();                                                             \
    __builtin_amdgcn_s_setprio(1);                                       \
    MM4(af, bfL, 4, 0);                                                  \
    __builtin_amdgcn_s_setprio(0);                                       \
    if ((KT) + 1 < NKT) {                                                \
      LDA4T(af, AO, 0);               /* af_lo(KT+1) */                  \
      LDB2T(bfL, BO, 0);              /* bf_lo(KT+1) */                  \
    }                                                                    \
    SB0();                                                               \
    BAR();                                                               \
  } while (0)

__global__ __launch_bounds__(512, 2) void scl_gemm(
    const float* __restrict__ xg, const int* __restrict__ subject_id,
    const float* __restrict__ wg, const float* __restrict__ bias,
    float* __restrict__ out) {
  __shared__ __align__(16) unsigned short As[2][BM * BK];  // 64 KiB
  __shared__ __align__(16) unsigned short Bs[2][BN * BK];  // 64 KiB

  const int tid = threadIdx.x;
  const int lane = tid & 63;
  const int wid = tid >> 6;   // 0..7
  const int wr = wid >> 2;    // 0..1  (M half)
  const int wc = wid & 3;     // 0..3  (N quarter)
  const int lcol = lane & 15;
  const int lq = lane >> 4;   // 0..3
  const int rl = lane >> 3;   // 0..7 (staging row-in-group)
  const int pc0 = lq ^ (lane & 7);  // phys chunk for kk=0 (XOR swizzle)

  // XCD-grouped bijective block map: xcd = bid&7 owns batches 4*xcd..4*xcd+3.
  const int bid = blockIdx.x;
  const int b = (bid & 7) * 4 + ((bid >> 3) & 3);
  const int t = bid >> 5;          // 0..7
  const int n0 = (t & 1) * BM;
  const int o0 = (t >> 1) * BN;
  const int sid = subject_id[b];

  // Staging: thread handles rows wid*32 + i*8 + rl, logical chunk (lane&7)^rl,
  // written at phys chunk lane&7 (so logical c of row r lands at c^(r&7)).
  const int skc = ((lane & 7) ^ rl) << 3;  // f32 elems? no: element offset
  const float* agA =
      xg + (size_t)(b * N_DIM + n0 + wid * 32 + rl) * H_DIM + skc;
  const float* bgB =
      wg + (size_t)(sid * O_DIM + o0 + wid * 32 + rl) * H_DIM + skc;
  const int swoff = (wid * 32 + rl) * BK + (lane & 7) * 8;  // shorts

  unsigned short* const As0 = &As[0][0];
  unsigned short* const As1 = &As[1][0];
  unsigned short* const Bs0 = &Bs[0][0];
  unsigned short* const Bs1 = &Bs[1][0];

  f32x4 acc[8][4];
#pragma unroll
  for (int mi = 0; mi < 8; ++mi)
#pragma unroll
    for (int ni = 0; ni < 4; ++ni) {
      f32x4 z = {0.f, 0.f, 0.f, 0.f};
      acc[mi][ni] = z;
    }

  bf16x8 af[4][2];   // ping-pong: lo(kt) during P0/P1, hi(kt) during P2/P3
  bf16x8 bfL[2][2];  // B lo-n pair, live P0..P3
  bf16x8 bfH[2][2];  // B hi-n pair, live P1..P2
  f32x4 ga[4][2];    // staged A f32 (1-phase lifetime)
  f32x4 gb[4][2];    // staged B f32 (1-phase lifetime)

  // Prologue: stage kt=0 through regs (serial, once).
  GLOADA(0);
  VMW(0);
  DSWR(ga, As0);
  GLOADB(0);
  VMW(0);
  DSWR(gb, Bs0);
  LGKMW(0);
  BAR();
  LDA4T(af, As0, 0);   // af_lo(0)
  LDB2T(bfL, Bs0, 0);  // bf_lo(0)
  SB0();

#pragma unroll 1
  for (int kt = 0; kt < NKT; kt += 2) {
    KTILE(kt, As0, Bs0, As1, Bs1);
    KTILE(kt + 1, As1, Bs1, As0, Bs0);
  }

  // Epilogue: C/D layout col = lane&15, row = (lane>>4)*4 + reg.
  float bv[4];
#pragma unroll
  for (int ni = 0; ni < 4; ++ni)
    bv[ni] = bias[sid * O_DIM + o0 + wc * 64 + ni * 16 + lcol];

  float* outb =
      out + (size_t)(b * N_DIM + n0 + wr * 128) * O_DIM + o0 + wc * 64 + lcol;
#pragma unroll
  for (int mi = 0; mi < 8; ++mi) {
#pragma unroll
    for (int r = 0; r < 4; ++r) {
      float* orow = outb + (size_t)(mi * 16 + lq * 4 + r) * O_DIM;
#pragma unroll
      for (int ni = 0; ni < 4; ++ni)
        orow[ni * 16] = acc[mi][ni][r] + bv[ni];
    }
  }
}

extern "C" void kernel_launch(void* const* d_in, const int* in_sizes, int n_in,
                              void* d_out, int out_size, void* d_ws, size_t ws_size,
                              hipStream_t stream) {
  const float* x = (const float*)d_in[0];
  const int* subject_id = (const int*)d_in[1];
  const float* weight = (const float*)d_in[2];
  const float* bias = (const float*)d_in[3];
  float* out = (float*)d_out;

  scl_gemm<<<256, 512, 0, stream>>>(x, subject_id, weight, bias, out);
}

// Round 5
// 178.404 us; speedup vs baseline: 1.4534x; 1.4534x over previous
//
#include <hip/hip_runtime.h>

// SubjectConditionalLinear: y[b,n,o] = sum_h x[b,n,h] * W[sid[b],o,h] + bias[sid[b],o]
// x: [32,512,1024] f32, subject_id: [32] i32, weight: [8,1024,1024] f32, bias: [8,1024] f32
// out: [32,512,1024] f32
//
// R9: R8 spilled (non-acc VGPR budget is 128 = 256 unified cap - 128 AGPR acc;
// ga+gb+frags+addr > 128 -> 220MB scratch writes). Fix: reg-stage ONLY A
// (x f32 -> cvt_pk -> ds_write into R6's byte-identical LDS layout; ga=32 VGPR),
// keep B on the proven global_load_lds bf16 path (zero VGPR), fed by the small
// cvt_w pass (48MB). x's 96MB round-trip eliminated; budget ~90 < 128.
//
// Ledger per kt (2 LDS bufs, 4 snake phases, 1 barrier each):
//  P0-tail: issue A-gloads(kt+1) x8 (vm); hoisted bfH(kt) ds_reads.
//  P1-tail: issue B global_load_lds(kt+1) x4 (vm); hoisted afH(kt) ds_reads.
//  P2-tail: VMW(4) retires A (B may fly); cvt+ds_write A(kt+1)->AO;
//           VMW(0) retires B DMA; LGKMW(0) publishes writes; BAR.
//  P3-tail: hoisted afL/bfL(kt+1) reads — A published & B retired by ALL
//           waves before the P2-end barrier (cross-wave safe, deterministic).

constexpr int S_DIM = 8;
constexpr int O_DIM = 1024;
constexpr int H_DIM = 1024;
constexpr int B_DIM = 32;
constexpr int N_DIM = 512;

constexpr int BM = 256;
constexpr int BN = 256;
constexpr int BK = 64;
constexpr int NKT = H_DIM / BK;  // 16 K-tiles

typedef short bf16x8 __attribute__((ext_vector_type(8)));
typedef float f32x4 __attribute__((ext_vector_type(4)));
typedef float f32x2 __attribute__((ext_vector_type(2)));
typedef __bf16 bf16x2 __attribute__((ext_vector_type(2)));
typedef unsigned int u32x4 __attribute__((ext_vector_type(4)));

__device__ __forceinline__ unsigned int cvt_pk_bf16(float a, float b) {
  f32x2 v;
  v[0] = a;
  v[1] = b;
  bf16x2 r = __builtin_convertvector(v, bf16x2);  // v_cvt_pk_bf16_f32
  return __builtin_bit_cast(unsigned int, r);
}

__device__ __forceinline__ void gload_lds16(const void* g, void* l) {
  __builtin_amdgcn_global_load_lds(
      (const __attribute__((address_space(1))) unsigned int*)g,
      (__attribute__((address_space(3))) unsigned int*)l, 16, 0, 0);
}

// ---------- Phase 1: fp32 -> bf16 convert, WEIGHTS ONLY (48 MB) ------------
__global__ __launch_bounds__(256) void cvt_w(const float* __restrict__ w,
                                             unsigned short* __restrict__ wb) {
  const long long e0 = (long long)blockIdx.x * 4096 + threadIdx.x * 4;
#pragma unroll
  for (int c = 0; c < 4; ++c) {
    const f32x4 v = __builtin_nontemporal_load((const f32x4*)(w + e0 + c * 1024));
    uint2 u;
    u.x = cvt_pk_bf16(v[0], v[1]);
    u.y = cvt_pk_bf16(v[2], v[3]);
    *(uint2*)(wb + e0 + c * 1024) = u;
  }
}

// ---------- Phase 2: fused GEMM ---------------------------------------------
#define BAR() __builtin_amdgcn_s_barrier()
#define SB0() __builtin_amdgcn_sched_barrier(0)
#define VMW(N) asm volatile("s_waitcnt vmcnt(" #N ")" ::: "memory")
#define LGKMW(N) asm volatile("s_waitcnt lgkmcnt(" #N ")" ::: "memory")
#define LGKM0()                                            \
  do {                                                     \
    asm volatile("s_waitcnt lgkmcnt(0)" ::: "memory");     \
    __builtin_amdgcn_sched_barrier(0);                     \
  } while (0)

// ---- fragment reads (R6-identical geometry) -------------------------------
#define LDA4T(DST, ABUF, MB)                                             \
  do {                                                                   \
    _Pragma("unroll") for (int m_ = 0; m_ < 4; ++m_) {                   \
      const int ar_ = wr * 128 + ((MB) + m_) * 16 + lcol;                \
      const unsigned short* ap_ = (ABUF) + ar_ * BK;                     \
      DST[m_][0] = *(const bf16x8*)(ap_ + (pc0 << 3));                   \
      DST[m_][1] = *(const bf16x8*)(ap_ + ((pc0 ^ 4) << 3));             \
    }                                                                    \
  } while (0)

#define LDB2T(DST, BBUF, NB)                                             \
  do {                                                                   \
    _Pragma("unroll") for (int n_ = 0; n_ < 2; ++n_) {                   \
      const int br_ = wc * 64 + ((NB) + n_) * 16 + lcol;                 \
      const unsigned short* bp_ = (BBUF) + br_ * BK;                     \
      DST[n_][0] = *(const bf16x8*)(bp_ + (pc0 << 3));                   \
      DST[n_][1] = *(const bf16x8*)(bp_ + ((pc0 ^ 4) << 3));             \
    }                                                                    \
  } while (0)

#define MM4(AF, BF, MB, NB)                                                 \
  do {                                                                      \
    _Pragma("unroll") for (int m_ = 0; m_ < 4; ++m_)                        \
    _Pragma("unroll") for (int n_ = 0; n_ < 2; ++n_)                        \
    _Pragma("unroll") for (int x_ = 0; x_ < 2; ++x_)                        \
      acc[(MB) + m_][(NB) + n_] = __builtin_amdgcn_mfma_f32_16x16x32_bf16(  \
          AF[m_][x_], BF[n_][x_], acc[(MB) + m_][(NB) + n_], 0, 0, 0);      \
  } while (0)

// ---- A reg-staging: global f32 -> VGPR -> cvt -> ds_write bf16 ------------
// Thread covers rows wid*32 + i*8 + rl (i=0..3), logical k-chunk (lane&7)^rl,
// written to phys chunk lane&7 of its row (R6 swizzle: logical c -> c^(r&7)).
#define GLOADA(KT)                                                         \
  do {                                                                     \
    _Pragma("unroll") for (int i_ = 0; i_ < 4; ++i_) {                     \
      const float* p_ = agA + (size_t)i_ * 8 * H_DIM + (size_t)(KT) * 64;  \
      ga[i_][0] = *(const f32x4*)p_;                                       \
      ga[i_][1] = *(const f32x4*)(p_ + 4);                                 \
    }                                                                      \
  } while (0)

#define DSWRA(DST)                                                         \
  do {                                                                     \
    _Pragma("unroll") for (int i_ = 0; i_ < 4; ++i_) {                     \
      u32x4 t_;                                                            \
      t_[0] = cvt_pk_bf16(ga[i_][0][0], ga[i_][0][1]);                     \
      t_[1] = cvt_pk_bf16(ga[i_][0][2], ga[i_][0][3]);                     \
      t_[2] = cvt_pk_bf16(ga[i_][1][0], ga[i_][1][1]);                     \
      t_[3] = cvt_pk_bf16(ga[i_][1][2], ga[i_][1][3]);                     \
      *(u32x4*)((DST) + swoff + i_ * 8 * BK) = t_;                         \
    }                                                                      \
  } while (0)

// ---- B staging via global_load_lds (R6-identical) -------------------------
#define STAGE_B(S, DST, KT)                                                 \
  do {                                                                      \
    gload_lds16(bgB0 + (size_t)((S) * 32) * H_DIM + (size_t)(KT) * 64,      \
                (DST) + (bq0 + (S) * 32) * BK);                             \
    gload_lds16(bgB1 + (size_t)((S) * 32) * H_DIM + (size_t)(KT) * 64,      \
                (DST) + (bq1 + (S) * 32) * BK);                             \
  } while (0)

// One K-tile, 4 snake phases, 1 barrier each.
#define KTILE(KT, AC, BC, AO, BO)                                        \
  do {                                                                   \
    /* P0: Q(lo-m, lo-n) — af=lo(KT), bfL(KT) read in prev P3 tail */    \
    LGKM0();                                                             \
    __builtin_amdgcn_s_setprio(1);                                       \
    MM4(af, bfL, 0, 0);                                                  \
    __builtin_amdgcn_s_setprio(0);                                       \
    if ((KT) + 1 < NKT) GLOADA((KT) + 1);                                \
    LDB2T(bfH, BC, 2);                /* bf_hi(KT) for P1 */             \
    SB0();                                                               \
    BAR();                                                               \
    /* P1: Q(lo-m, hi-n) */                                              \
    LGKM0();                                                             \
    __builtin_amdgcn_s_setprio(1);                                       \
    MM4(af, bfH, 0, 2);                                                  \
    __builtin_amdgcn_s_setprio(0);                                       \
    if ((KT) + 1 < NKT) {                                                \
      STAGE_B(0, BO, (KT) + 1);                                          \
      STAGE_B(1, BO, (KT) + 1);                                          \
    }                                                                    \
    LDA4T(af, AC, 4);                 /* af_hi(KT) for P2/P3 */          \
    SB0();                                                               \
    BAR();                                                               \
    /* P2: Q(hi-m, hi-n) */                                              \
    LGKM0();                                                             \
    __builtin_amdgcn_s_setprio(1);                                       \
    MM4(af, bfH, 4, 2);                                                  \
    __builtin_amdgcn_s_setprio(0);                                       \
    if ((KT) + 1 < NKT) {                                                \
      VMW(4);        /* A(KT+1) regs landed; 4 B-DMA may fly */          \
      DSWRA(AO);                                                         \
      VMW(0);        /* B(KT+1) DMA retired (issued 1 phase ago) */      \
      LGKMW(0);      /* publish A ds_writes before BAR */                \
    }                                                                    \
    SB0();                                                               \
    BAR();                                                               \
    /* P3: Q(hi-m, lo-n) */                                              \
    LGKM0();                                                             \
    __builtin_amdgcn_s_setprio(1);                                       \
    MM4(af, bfL, 4, 0);                                                  \
    __builtin_amdgcn_s_setprio(0);                                       \
    if ((KT) + 1 < NKT) {                                                \
      LDA4T(af, AO, 0);               /* af_lo(KT+1) */                  \
      LDB2T(bfL, BO, 0);              /* bf_lo(KT+1) */                  \
    }                                                                    \
    SB0();                                                               \
    BAR();                                                               \
  } while (0)

__global__ __launch_bounds__(512, 2) void scl_gemm(
    const float* __restrict__ xg, const int* __restrict__ subject_id,
    const unsigned short* __restrict__ wb, const float* __restrict__ bias,
    float* __restrict__ out) {
  __shared__ __align__(16) unsigned short As[2][BM * BK];  // 64 KiB
  __shared__ __align__(16) unsigned short Bs[2][BN * BK];  // 64 KiB

  const int tid = threadIdx.x;
  const int lane = tid & 63;
  const int wid = tid >> 6;   // 0..7
  const int wr = wid >> 2;    // 0..1  (M half)
  const int wc = wid & 3;     // 0..3  (N quarter)
  const int lcol = lane & 15;
  const int lq = lane >> 4;   // 0..3
  const int rl = lane >> 3;   // 0..7 (staging row-in-group)
  const int pc0 = lq ^ (lane & 7);  // phys chunk for kk=0 (XOR swizzle)

  // XCD-grouped bijective block map: xcd = bid&7 owns batches 4*xcd..4*xcd+3.
  const int bid = blockIdx.x;
  const int b = (bid & 7) * 4 + ((bid >> 3) & 3);
  const int t = bid >> 5;          // 0..7
  const int n0 = (t & 1) * BM;
  const int o0 = (t >> 1) * BN;
  const int sid = subject_id[b];

  // A reg-staging base (f32): rows wid*32 + rl, logical chunk (lane&7)^rl.
  const int skc = ((lane & 7) ^ rl) << 3;
  const float* agA =
      xg + (size_t)(b * N_DIM + n0 + wid * 32 + rl) * H_DIM + skc;
  const int swoff = (wid * 32 + rl) * BK + (lane & 7) * 8;  // shorts

  // B DMA bases (bf16, R6-identical strip mapping).
  const int bq0 = ((wid * 2) >> 2) * 64 + ((wid * 2) & 3) * 8;
  const int bq1 = ((wid * 2 + 1) >> 2) * 64 + ((wid * 2 + 1) & 3) * 8;
  const unsigned short* bgB0 =
      wb + (size_t)(sid * O_DIM + o0 + bq0 + rl) * H_DIM + skc;
  const unsigned short* bgB1 =
      wb + (size_t)(sid * O_DIM + o0 + bq1 + rl) * H_DIM + skc;

  unsigned short* const As0 = &As[0][0];
  unsigned short* const As1 = &As[1][0];
  unsigned short* const Bs0 = &Bs[0][0];
  unsigned short* const Bs1 = &Bs[1][0];

  f32x4 acc[8][4];
#pragma unroll
  for (int mi = 0; mi < 8; ++mi)
#pragma unroll
    for (int ni = 0; ni < 4; ++ni) {
      f32x4 z = {0.f, 0.f, 0.f, 0.f};
      acc[mi][ni] = z;
    }

  bf16x8 af[4][2];   // ping-pong: lo(kt) during P0/P1, hi(kt) during P2/P3
  bf16x8 bfL[2][2];  // B lo-n pair, live P0..P3
  bf16x8 bfH[2][2];  // B hi-n pair, live P1..P2
  f32x4 ga[4][2];    // staged A f32 (P0-tail .. P2-tail lifetime)

  // Prologue: stage kt=0 (A via regs, B via DMA), then first fragment reads.
  GLOADA(0);
  STAGE_B(0, Bs0, 0);
  STAGE_B(1, Bs0, 0);
  VMW(4);   // A regs landed (4 B-DMA may fly)
  DSWRA(As0);
  VMW(0);   // B DMA retired
  LGKMW(0);
  BAR();
  LDA4T(af, As0, 0);   // af_lo(0)
  LDB2T(bfL, Bs0, 0);  // bf_lo(0)
  SB0();

#pragma unroll 1
  for (int kt = 0; kt < NKT; kt += 2) {
    KTILE(kt, As0, Bs0, As1, Bs1);
    KTILE(kt + 1, As1, Bs1, As0, Bs0);
  }

  // Epilogue: C/D layout col = lane&15, row = (lane>>4)*4 + reg.
  float bv[4];
#pragma unroll
  for (int ni = 0; ni < 4; ++ni)
    bv[ni] = bias[sid * O_DIM + o0 + wc * 64 + ni * 16 + lcol];

  float* outb =
      out + (size_t)(b * N_DIM + n0 + wr * 128) * O_DIM + o0 + wc * 64 + lcol;
#pragma unroll
  for (int mi = 0; mi < 8; ++mi) {
#pragma unroll
    for (int r = 0; r < 4; ++r) {
      float* orow = outb + (size_t)(mi * 16 + lq * 4 + r) * O_DIM;
#pragma unroll
      for (int ni = 0; ni < 4; ++ni)
        orow[ni * 16] = acc[mi][ni][r] + bv[ni];
    }
  }
}

extern "C" void kernel_launch(void* const* d_in, const int* in_sizes, int n_in,
                              void* d_out, int out_size, void* d_ws, size_t ws_size,
                              hipStream_t stream) {
  const float* x = (const float*)d_in[0];
  const int* subject_id = (const int*)d_in[1];
  const float* weight = (const float*)d_in[2];
  const float* bias = (const float*)d_in[3];
  float* out = (float*)d_out;

  unsigned short* wb = (unsigned short*)d_ws;  // 16 MiB

  cvt_w<<<2048, 256, 0, stream>>>(weight, wb);

  scl_gemm<<<256, 512, 0, stream>>>(x, subject_id, wb, bias, out);
}

// Round 6
// 178.149 us; speedup vs baseline: 1.4555x; 1.0014x over previous
//
#include <hip/hip_runtime.h>

// SubjectConditionalLinear: y[b,n,o] = sum_h x[b,n,h] * W[sid[b],o,h] + bias[sid[b],o]
// x: [32,512,1024] f32, subject_id: [32] i32, weight: [8,1024,1024] f32, bias: [8,1024] f32
// out: [32,512,1024] f32
//
// R10: split design locked in (R7/R8/R9 proved fusion of the f32->bf16 stream
// into the barrier-locked gemm is structurally bad: lockstep serial work +
// exposed drains). gemm = R6 verbatim (measured 43.6us, 0 conflicts).
// cvt rebuilt for 16B/lane stores (was 8B): 4 iters of {2x16B NT loads ->
// 1x16B cached store}, 8192 elems/block, 3072 blocks. Target ~5.5+ TB/s.

constexpr int S_DIM = 8;
constexpr int O_DIM = 1024;
constexpr int H_DIM = 1024;
constexpr int B_DIM = 32;
constexpr int N_DIM = 512;

constexpr int BM = 256;
constexpr int BN = 256;
constexpr int BK = 64;
constexpr int NKT = H_DIM / BK;  // 16 K-tiles

constexpr long long X_ELEMS = (long long)B_DIM * N_DIM * H_DIM;   // 16,777,216
constexpr size_t XB_BYTES = (size_t)X_ELEMS * 2;                  // 32 MiB

typedef short bf16x8 __attribute__((ext_vector_type(8)));
typedef float f32x4 __attribute__((ext_vector_type(4)));
typedef float f32x2 __attribute__((ext_vector_type(2)));
typedef __bf16 bf16x2 __attribute__((ext_vector_type(2)));
typedef unsigned int u32x4 __attribute__((ext_vector_type(4)));

__device__ __forceinline__ unsigned int cvt_pk_bf16(float a, float b) {
  f32x2 v;
  v[0] = a;
  v[1] = b;
  bf16x2 r = __builtin_convertvector(v, bf16x2);  // v_cvt_pk_bf16_f32
  return __builtin_bit_cast(unsigned int, r);
}

__device__ __forceinline__ void gload_lds16(const void* g, void* l) {
  __builtin_amdgcn_global_load_lds(
      (const __attribute__((address_space(1))) unsigned int*)g,
      (__attribute__((address_space(3))) unsigned int*)l, 16, 0, 0);
}

// ---------- Phase 1: fp32 -> bf16 convert (x and all 8 weight matrices) ----
// 16B/lane stores (coalescing sweet spot). Block covers 8192 contiguous f32:
// x = 16,777,216 -> 2048 blocks; w = 8,388,608 -> 1024 blocks.
__global__ __launch_bounds__(256) void cvt_kernel(
    const float* __restrict__ x, const float* __restrict__ w,
    unsigned short* __restrict__ xb, unsigned short* __restrict__ wb) {
  const int blk = blockIdx.x;
  const float* src;
  unsigned short* dst;
  long long base;
  if (blk < 2048) {
    src = x; dst = xb; base = (long long)blk * 8192;
  } else {
    src = w; dst = wb; base = (long long)(blk - 2048) * 8192;
  }
  const long long e0 = base + threadIdx.x * 8;
#pragma unroll
  for (int c = 0; c < 4; ++c) {
    const f32x4 v0 =
        __builtin_nontemporal_load((const f32x4*)(src + e0 + c * 2048));
    const f32x4 v1 =
        __builtin_nontemporal_load((const f32x4*)(src + e0 + c * 2048 + 4));
    u32x4 u;
    u[0] = cvt_pk_bf16(v0[0], v0[1]);
    u[1] = cvt_pk_bf16(v0[2], v0[3]);
    u[2] = cvt_pk_bf16(v1[0], v1[1]);
    u[3] = cvt_pk_bf16(v1[2], v1[3]);
    *(u32x4*)(dst + e0 + c * 2048) = u;  // cached: gemm re-reads from L3
  }
}

// ---------- Phase 2: bf16 MFMA GEMM, hoisted-read pipeline (R6 verbatim) ---
#define BAR() __builtin_amdgcn_s_barrier()
#define SB0() __builtin_amdgcn_sched_barrier(0)
#define VMW(N) asm volatile("s_waitcnt vmcnt(" #N ")" ::: "memory")
#define LGKM0()                                            \
  do {                                                     \
    asm volatile("s_waitcnt lgkmcnt(0)" ::: "memory");     \
    __builtin_amdgcn_sched_barrier(0);                     \
  } while (0)

// A-fragment quad into DST: rows wr*128 + (MB..MB+3)*16 + lcol, both kk halves.
#define LDA4T(DST, ABUF, MB)                                             \
  do {                                                                   \
    _Pragma("unroll") for (int m_ = 0; m_ < 4; ++m_) {                   \
      const int ar_ = wr * 128 + ((MB) + m_) * 16 + lcol;                \
      const unsigned short* ap_ = (ABUF) + ar_ * BK;                     \
      DST[m_][0] = *(const bf16x8*)(ap_ + (pc0 << 3));                   \
      DST[m_][1] = *(const bf16x8*)(ap_ + ((pc0 ^ 4) << 3));             \
    }                                                                    \
  } while (0)

// B-fragment pair into DST: rows wc*64 + (NB..NB+1)*16 + lcol, both kk halves.
#define LDB2T(DST, BBUF, NB)                                             \
  do {                                                                   \
    _Pragma("unroll") for (int n_ = 0; n_ < 2; ++n_) {                   \
      const int br_ = wc * 64 + ((NB) + n_) * 16 + lcol;                 \
      const unsigned short* bp_ = (BBUF) + br_ * BK;                     \
      DST[n_][0] = *(const bf16x8*)(bp_ + (pc0 << 3));                   \
      DST[n_][1] = *(const bf16x8*)(bp_ + ((pc0 ^ 4) << 3));             \
    }                                                                    \
  } while (0)

// One C-quadrant x K=64: 4m x 2n x 2kk = 16 MFMA.
#define MM4(AF, BF, MB, NB)                                                 \
  do {                                                                      \
    _Pragma("unroll") for (int m_ = 0; m_ < 4; ++m_)                        \
    _Pragma("unroll") for (int n_ = 0; n_ < 2; ++n_)                        \
    _Pragma("unroll") for (int x_ = 0; x_ < 2; ++x_)                        \
      acc[(MB) + m_][(NB) + n_] = __builtin_amdgcn_mfma_f32_16x16x32_bf16(  \
          AF[m_][x_], BF[n_][x_], acc[(MB) + m_][(NB) + n_], 0, 0, 0);      \
  } while (0)

// Stage A half H (rows {H*64+wid*8+rl, 128+H*64+wid*8+rl}) of K-tile KT.
#define STAGE_A(H, DST, KT)                                                 \
  do {                                                                      \
    gload_lds16(agA + (size_t)((H) * 64) * H_DIM + (KT) * 64,               \
                (DST) + ((H) * 64 + wid * 8) * BK);                         \
    gload_lds16(agA + (size_t)((H) * 64 + 128) * H_DIM + (KT) * 64,         \
                (DST) + ((H) * 64 + 128 + wid * 8) * BK);                   \
  } while (0)

// Stage B strip S of K-tile KT.
#define STAGE_B(S, DST, KT)                                                 \
  do {                                                                      \
    gload_lds16(bgB0 + (size_t)((S) * 32) * H_DIM + (KT) * 64,              \
                (DST) + (bq0 + (S) * 32) * BK);                             \
    gload_lds16(bgB1 + (size_t)((S) * 32) * H_DIM + (KT) * 64,              \
                (DST) + (bq1 + (S) * 32) * BK);                             \
  } while (0)

// One K-tile, 4 snake phases, 1 barrier each. Reads for phase p+1 issued in
// tail of phase p (after MFMA), covered by the VMW ledger.
#define KTILE(KT, AC, BC, AO, BO)                                        \
  do {                                                                   \
    /* P0: Q(lo-m, lo-n) — af=lo(KT), bfL(KT) read in prev P3 tail */    \
    LGKM0();                                                             \
    __builtin_amdgcn_s_setprio(1);                                       \
    MM4(af, bfL, 0, 0);                                                  \
    __builtin_amdgcn_s_setprio(0);                                       \
    LDB2T(bfH, BC, 2);                /* bf_hi(KT) for P1 */             \
    if ((KT) + 1 < NKT) STAGE_A(1, AO, (KT) + 1);                        \
    SB0();                                                               \
    BAR();                                                               \
    /* P1: Q(lo-m, hi-n) */                                              \
    LGKM0();                                                             \
    __builtin_amdgcn_s_setprio(1);                                       \
    MM4(af, bfH, 0, 2);                                                  \
    __builtin_amdgcn_s_setprio(0);                                       \
    LDA4T(af, AC, 4);                 /* af_hi(KT) for P2/P3 */          \
    if ((KT) + 1 < NKT) STAGE_B(1, BO, (KT) + 1);                        \
    SB0();                                                               \
    BAR();                                                               \
    /* P2: Q(hi-m, hi-n) */                                              \
    LGKM0();                                                             \
    __builtin_amdgcn_s_setprio(1);                                       \
    MM4(af, bfH, 4, 2);                                                  \
    __builtin_amdgcn_s_setprio(0);                                       \
    if ((KT) + 2 < NKT) {                                                \
      STAGE_A(0, AC, (KT) + 2);                                          \
      STAGE_B(0, BC, (KT) + 2);                                          \
      VMW(8);  /* retire A0(KT+1),B0(KT+1) for P3-tail reads */          \
    } else if ((KT) + 2 == NKT) {                                        \
      VMW(4);                                                            \
    }                                                                    \
    SB0();                                                               \
    BAR();                                                               \
    /* P3: Q(hi-m, lo-n) */                                              \
    LGKM0();                                                             \
    __builtin_amdgcn_s_setprio(1);                                       \
    MM4(af, bfL, 4, 0);                                                  \
    __builtin_amdgcn_s_setprio(0);                                       \
    if ((KT) + 1 < NKT) {                                                \
      LDA4T(af, AO, 0);               /* af_lo(KT+1) */                  \
      LDB2T(bfL, BO, 0);              /* bf_lo(KT+1) */                  \
      if ((KT) + 2 < NKT) VMW(4);  /* retire A1(KT+1),B1(KT+1) */        \
      else VMW(0);                 /* KT==NKT-2: drain for last tile */  \
    }                                                                    \
    SB0();                                                               \
    BAR();                                                               \
  } while (0)

__global__ __launch_bounds__(512, 2) void scl_gemm(
    const unsigned short* __restrict__ xb, const int* __restrict__ subject_id,
    const unsigned short* __restrict__ wb, const float* __restrict__ bias,
    float* __restrict__ out) {
  __shared__ __align__(16) unsigned short As[2][BM * BK];  // 64 KiB
  __shared__ __align__(16) unsigned short Bs[2][BN * BK];  // 64 KiB

  const int tid = threadIdx.x;
  const int lane = tid & 63;
  const int wid = tid >> 6;   // 0..7
  const int wr = wid >> 2;    // 0..1  (M half)
  const int wc = wid & 3;     // 0..3  (N quarter)
  const int lcol = lane & 15;
  const int lq = lane >> 4;   // 0..3
  const int rl = lane >> 3;   // 0..7 (staging row-in-group)
  const int pc0 = lq ^ (lane & 7);  // phys chunk for kk=0 (XOR swizzle)

  // XCD-grouped bijective block map: xcd = bid&7 owns batches 4*xcd..4*xcd+3.
  const int bid = blockIdx.x;
  const int b = (bid & 7) * 4 + ((bid >> 3) & 3);
  const int t = bid >> 5;          // 0..7
  const int n0 = (t & 1) * BM;
  const int o0 = (t >> 1) * BN;
  const int sid = subject_id[b];

  // Staging global bases. Lane L covers phys chunk L&7 of row rl;
  // logical chunk = (L&7)^rl (row&7 == rl since all row bases are x8).
  const int skc = ((lane & 7) ^ rl) << 3;
  const unsigned short* agA =
      xb + (size_t)(b * N_DIM + n0 + wid * 8 + rl) * H_DIM + skc;
  const int bq0 = ((wid * 2) >> 2) * 64 + ((wid * 2) & 3) * 8;
  const int bq1 = ((wid * 2 + 1) >> 2) * 64 + ((wid * 2 + 1) & 3) * 8;
  const unsigned short* bgB0 =
      wb + (size_t)(sid * O_DIM + o0 + bq0 + rl) * H_DIM + skc;
  const unsigned short* bgB1 =
      wb + (size_t)(sid * O_DIM + o0 + bq1 + rl) * H_DIM + skc;

  unsigned short* const As0 = &As[0][0];
  unsigned short* const As1 = &As[1][0];
  unsigned short* const Bs0 = &Bs[0][0];
  unsigned short* const Bs1 = &Bs[1][0];

  f32x4 acc[8][4];
#pragma unroll
  for (int mi = 0; mi < 8; ++mi)
#pragma unroll
    for (int ni = 0; ni < 4; ++ni) {
      f32x4 z = {0.f, 0.f, 0.f, 0.f};
      acc[mi][ni] = z;
    }

  bf16x8 af[4][2];   // ping-pong: lo(kt) during P0/P1, hi(kt) during P2/P3
  bf16x8 bfL[2][2];  // B lo-n pair, live P0..P3
  bf16x8 bfH[2][2];  // B hi-n pair, live P1..P2

  // Prologue stage stream (loads 1..12): A0(0) B0(0) A1(0) B1(0) A0(1) B0(1).
  STAGE_A(0, As0, 0);
  STAGE_B(0, Bs0, 0);
  STAGE_A(1, As0, 0);
  STAGE_B(1, Bs0, 0);
  STAGE_A(0, As1, 1);
  STAGE_B(0, Bs1, 1);
  VMW(4);  // retire A0(0),B0(0),A1(0),B1(0); leave A0(1),B0(1) in flight
  BAR();
  LDA4T(af, As0, 0);   // af_lo(0)
  LDB2T(bfL, Bs0, 0);  // bf_lo(0)
  SB0();

#pragma unroll 1
  for (int kt = 0; kt < NKT; kt += 2) {
    KTILE(kt, As0, Bs0, As1, Bs1);
    KTILE(kt + 1, As1, Bs1, As0, Bs0);
  }

  // Epilogue: C/D layout col = lane&15, row = (lane>>4)*4 + reg.
  float bv[4];
#pragma unroll
  for (int ni = 0; ni < 4; ++ni)
    bv[ni] = bias[sid * O_DIM + o0 + wc * 64 + ni * 16 + lcol];

  float* outb =
      out + (size_t)(b * N_DIM + n0 + wr * 128) * O_DIM + o0 + wc * 64 + lcol;
#pragma unroll
  for (int mi = 0; mi < 8; ++mi) {
#pragma unroll
    for (int r = 0; r < 4; ++r) {
      float* orow = outb + (size_t)(mi * 16 + lq * 4 + r) * O_DIM;
#pragma unroll
      for (int ni = 0; ni < 4; ++ni)
        orow[ni * 16] = acc[mi][ni][r] + bv[ni];
    }
  }
}

extern "C" void kernel_launch(void* const* d_in, const int* in_sizes, int n_in,
                              void* d_out, int out_size, void* d_ws, size_t ws_size,
                              hipStream_t stream) {
  const float* x = (const float*)d_in[0];
  const int* subject_id = (const int*)d_in[1];
  const float* weight = (const float*)d_in[2];
  const float* bias = (const float*)d_in[3];
  float* out = (float*)d_out;

  unsigned short* xb = (unsigned short*)d_ws;                       // 32 MiB
  unsigned short* wb = (unsigned short*)((char*)d_ws + XB_BYTES);   // 16 MiB

  cvt_kernel<<<3072, 256, 0, stream>>>(x, weight, xb, wb);

  scl_gemm<<<256, 512, 0, stream>>>(xb, subject_id, wb, bias, out);
}